// Round 1
// baseline (139.199 us; speedup 1.0000x reference)
//
#include <hip/hip_runtime.h>
#include <cstdint>
#include <cstddef>

// ---------------------------------------------------------------------------
// logsumexp_m[ -0.5*||(s_n - x_m)/std||^2 ] + logc - log M   (N=8192,M=4096,D=784)
// R5: 256x256 tile, 8 waves (wave = 128x64), m201-style phased schedule:
//  - ring of 4 x 32KB kt64 LDS slots; half-tile staging, counted vmcnt(8)
//    across the per-tile barrier (never vmcnt(0) mid-loop)
//  - 4 phases per K-tile: {ds_read subtile; barrier; lgkmcnt(0); setprio(1);
//    8 MFMA; setprio(0); barrier}
//  - R2's measured-conflict-free slot swizzle kept: slot = chunk^((row>>1)&3),
//    pre-swizzled GLOBAL source + linear global_load_lds dest + swizzled read
//  - conflict-free epilogue: [256][64] float2 partials overlay the 128KB LDS
//    (4 words/bank uniform), rotated-index scan; 16 partials/row to global.
// ---------------------------------------------------------------------------

#define N_ROWS 8192
#define M_ROWS 4096
#define D_DIM  784
#define KPB    896        // K bytes per row (fp8), padded 784 -> 7*128
#define LOG2PI 1.8378770664093453f
#define LOGM   8.317766166719343f   // log(4096)

typedef unsigned char u8;
typedef __attribute__((ext_vector_type(8))) int   i32x8;
typedef __attribute__((ext_vector_type(4))) float f32x4;

__device__ __forceinline__ void gld16(const u8* g, u8* l) {
    __builtin_amdgcn_global_load_lds(
        (__attribute__((address_space(1))) void*)(void*)g,
        (__attribute__((address_space(3))) void*)l, 16, 0, 0);
}

// ------------- k_prep: scale, fp8-round, row norms (wave x 2 rows) ---------
// grid: 12288/8 = 1536 blocks (4 waves x 2 rows). Rows >= N_ROWS are x.
__global__ __launch_bounds__(256) void k_prep(const float* __restrict__ samples,
                                              const float* __restrict__ x,
                                              const float* __restrict__ stdv,
                                              u8* __restrict__ dst,
                                              float* __restrict__ norm) {
    const int wid = threadIdx.x >> 6, lane = threadIdx.x & 63;
    const int row0 = blockIdx.x * 8 + wid * 2;

    float4 rstd[4];
#pragma unroll
    for (int i = 0; i < 4; ++i) {
        int c = lane + 64 * i;
        rstd[i] = make_float4(1.f, 1.f, 1.f, 1.f);
        if (c < 196) {
            float4 d = ((const float4*)stdv)[c];
            rstd[i] = make_float4(1.f / d.x, 1.f / d.y, 1.f / d.z, 1.f / d.w);
        }
    }

#pragma unroll
    for (int rr = 0; rr < 2; ++rr) {
        const int row = row0 + rr;
        const float* src = (row < N_ROWS) ? samples + (size_t)row * D_DIM
                                          : x + (size_t)(row - N_ROWS) * D_DIM;
        unsigned* drow = (unsigned*)(dst + (size_t)row * KPB);
        float sq = 0.f;
#pragma unroll
        for (int i = 0; i < 4; ++i) {
            const int c = lane + 64 * i;       // u32 chunk (4 fp8)
            if (c < 224) {                     // 224*4 = 896 = KPB
                unsigned p = 0;
                if (c < 196) {                 // 196*4 = 784 = D
                    float4 s = ((const float4*)src)[c];
                    float ux = s.x * rstd[i].x, uy = s.y * rstd[i].y;
                    float uz = s.z * rstd[i].z, uw = s.w * rstd[i].w;
                    p = __builtin_amdgcn_cvt_pk_fp8_f32(ux, uy, 0, false);
                    p = __builtin_amdgcn_cvt_pk_fp8_f32(uz, uw, p, true);
                    float r0 = __builtin_amdgcn_cvt_f32_fp8(p, 0);
                    float r1 = __builtin_amdgcn_cvt_f32_fp8(p, 1);
                    float r2 = __builtin_amdgcn_cvt_f32_fp8(p, 2);
                    float r3 = __builtin_amdgcn_cvt_f32_fp8(p, 3);
                    sq += r0 * r0 + r1 * r1 + r2 * r2 + r3 * r3;  // norm of ROUNDED
                }
                drow[c] = p;
            }
        }
        for (int m = 32; m; m >>= 1) sq += __shfl_xor(sq, m);
        if (lane == 0) norm[row] = sq;
    }
}

// ---------------- k_gemm: 256x256 tile, fp8 MX K=128, phased ---------------
// LDS: 4 slots of 32KB (one kt64 half-tile each: A 256x64B @0, B 256x64B
// @+16384). Tile T reads slot pair ((2T)&3,(2T+1)&3) = contiguous 64KB at
// (T&1)*65536, so the 16x16x128 frag's two 64B k-halves sit at +0/+32768.
// Slot-of-16B: slot = chunk ^ ((row>>1)&3) (R2 conflict-free geometry).
// Waves: waveRow = wid>>2 (128-row half), waveCol = wid&3 (64-col quarter).
__global__ __launch_bounds__(512, 2) void k_gemm(const u8* __restrict__ U,
                                                 const u8* __restrict__ V,
                                                 const float* __restrict__ vnorm,
                                                 float* __restrict__ pmax,
                                                 float* __restrict__ psum) {
    __shared__ __align__(16) char smem[131072];
    float2* part = (float2*)smem;          // [256][64] epilogue partials (exact fit)

    const int tid = threadIdx.x;
    const int lane = tid & 63;
    const int wid = tid >> 6;              // 0..7
    const int waveRow = wid >> 2;          // 0..1
    const int waveCol = wid & 3;           // 0..3
    const int bCol = blockIdx.x;           // 0..15
    const int bRow = blockIdx.y;           // 0..31
    const int g = lane >> 4, rl = lane & 15;

    // ---- staging: per kt64 half u, 4 gld16/thread (2 A + 2 B) into slot u&3.
    const int r16 = lane >> 2, sl = lane & 3;
    const int gc16 = sl ^ ((r16 >> 1) & 3);          // pre-swizzled global granule
    const u8* gA[2]; const u8* gB[2]; int lo[2];
#pragma unroll
    for (int q = 0; q < 2; ++q) {
        const int rg = wid * 2 + q;                  // 16-row group 0..15
        gA[q] = U + (size_t)(bRow * 256 + rg * 16 + r16) * KPB + gc16 * 16;
        gB[q] = V + (size_t)(bCol * 256 + rg * 16 + r16) * KPB + gc16 * 16;
        lo[q] = rg * 1024;                           // wave-uniform LDS offset
    }

    // ---- hoisted frag-read offsets (lane k-bytes = 32*g of the 128B K-row)
    const int key = (rl >> 1) & 3;
    const int slotLo = (2 * (g & 1)) ^ key;
    const int aoff = (g >> 1) * 32768 + (waveRow * 128 + rl) * 64 + slotLo * 16; // +i*1024
    const int boff = (g >> 1) * 32768 + 16384 + (waveCol * 64 + rl) * 64 + slotLo * 16; // +j*1024

    f32x4 acc[8][4];
#pragma unroll
    for (int i = 0; i < 8; ++i)
#pragma unroll
        for (int j = 0; j < 4; ++j) acc[i][j] = (f32x4){0.f, 0.f, 0.f, 0.f};

#define ISSUE(u) { \
    u8* lb = (u8*)smem + ((u) & 3) * 32768; \
    const int ko = (u) * 64; \
    gld16(gA[0] + ko, lb + lo[0]); \
    gld16(gB[0] + ko, lb + 16384 + lo[0]); \
    gld16(gA[1] + ko, lb + lo[1]); \
    gld16(gB[1] + ko, lb + 16384 + lo[1]); }

    // prologue: 3 half-tiles in flight (12 loads/thread)
    ISSUE(0); ISSUE(1); ISSUE(2);

#pragma unroll
    for (int T = 0; T < 7; ++T) {
        if (T < 6) ISSUE(2 * T + 3);               // next tile's 2nd half
        if (T < 6) __builtin_amdgcn_s_waitcnt(0x0F78);  // vmcnt(8): tile T landed
        else       __builtin_amdgcn_s_waitcnt(0x0F70);  // vmcnt(0): last tile
        __builtin_amdgcn_s_barrier();              // all waves' staging of T done

        const char* base = smem + (T & 1) * 65536;
        i32x8 b[4], a[2];
#pragma unroll
        for (int ph = 0; ph < 4; ++ph) {
            if (ph == 0) {
#pragma unroll
                for (int j = 0; j < 4; ++j) {
                    int4 L = *(const int4*)(base + (boff + j * 1024));
                    int4 H = *(const int4*)(base + ((boff + j * 1024) ^ 16));
                    b[j] = (i32x8){L.x, L.y, L.z, L.w, H.x, H.y, H.z, H.w};
                }
            }
#pragma unroll
            for (int t = 0; t < 2; ++t) {
                const int i = ph * 2 + t;
                int4 L = *(const int4*)(base + (aoff + i * 1024));
                int4 H = *(const int4*)(base + ((aoff + i * 1024) ^ 16));
                a[t] = (i32x8){L.x, L.y, L.z, L.w, H.x, H.y, H.z, H.w};
            }
            __builtin_amdgcn_s_barrier();
            __builtin_amdgcn_s_waitcnt(0xC07F);    // lgkmcnt(0)
            __builtin_amdgcn_s_setprio(1);
#pragma unroll
            for (int t = 0; t < 2; ++t)
#pragma unroll
                for (int j = 0; j < 4; ++j)
                    acc[ph * 2 + t][j] = __builtin_amdgcn_mfma_scale_f32_16x16x128_f8f6f4(
                        a[t], b[j], acc[ph * 2 + t][j], 0 /*fp8*/, 0 /*fp8*/,
                        0, 127 /*scaleA=1*/, 0, 127 /*scaleB=1*/);
            __builtin_amdgcn_s_setprio(0);
            __builtin_amdgcn_s_barrier();
        }
        if (T < 5) ISSUE(2 * T + 4);               // next-next tile's 1st half
    }
#undef ISSUE
    __syncthreads();   // full drain before partials overlay

    // ---- epilogue: w = dot - 0.5*vn; per-lane reduce over j (4 cols), then
    // block reduce 64 partials/row via LDS. C/D: col = rl, row16 = g*4+reg.
    float vn[4];
#pragma unroll
    for (int j = 0; j < 4; ++j) vn[j] = vnorm[bCol * 256 + waveCol * 64 + j * 16 + rl];

    const int prow0 = waveRow * 128 + g * 4;
    const int pc = waveCol * 16 + rl;
#pragma unroll
    for (int i = 0; i < 8; ++i) {
#pragma unroll
        for (int rg = 0; rg < 4; ++rg) {
            float w0 = acc[i][0][rg] - 0.5f * vn[0];
            float w1 = acc[i][1][rg] - 0.5f * vn[1];
            float w2 = acc[i][2][rg] - 0.5f * vn[2];
            float w3 = acc[i][3][rg] - 0.5f * vn[3];
            float m = fmaxf(fmaxf(w0, w1), fmaxf(w2, w3));
            float s = __expf(w0 - m) + __expf(w1 - m) + __expf(w2 - m) + __expf(w3 - m);
            part[(prow0 + i * 16 + rg) * 64 + pc] = make_float2(m, s);
        }
    }
    __syncthreads();
    if (tid < 256) {
        const float2* p = part + tid * 64;
        const int rot = tid & 63;                  // rotate start: conflict-free scan
        float m = -3.4e38f;
#pragma unroll 8
        for (int q = 0; q < 64; ++q) m = fmaxf(m, p[(q + rot) & 63].x);
        float s = 0.f;
#pragma unroll 8
        for (int q = 0; q < 64; ++q) { float2 v = p[(q + rot) & 63]; s += v.y * __expf(v.x - m); }
        size_t grow = (size_t)(bRow * 256 + tid);
        pmax[grow * 16 + bCol] = m;
        psum[grow * 16 + bCol] = s;
    }
}

// --------------- k_final: combine 16 partials + row constants --------------
__global__ __launch_bounds__(256) void k_final(const float* __restrict__ pmax,
                                               const float* __restrict__ psum,
                                               const float* __restrict__ norm,
                                               const float* __restrict__ stdv,
                                               float* __restrict__ out) {
    __shared__ float wsum[4];
    const int t = threadIdx.x;
    float ls = 0.f;
    for (int d = t; d < D_DIM; d += 256) ls += logf(stdv[d]);
    for (int m = 32; m; m >>= 1) ls += __shfl_xor(ls, m);
    if ((t & 63) == 0) wsum[t >> 6] = ls;
    __syncthreads();
    const float logc = -0.5f * (float)D_DIM * LOG2PI - (wsum[0] + wsum[1] + wsum[2] + wsum[3]);

    const int n = blockIdx.x * 256 + t;
    const float* pm = pmax + (size_t)n * 16;
    const float* ps = psum + (size_t)n * 16;
    float gm = pm[0];
#pragma unroll
    for (int c = 1; c < 16; ++c) gm = fmaxf(gm, pm[c]);
    float S = 0.f;
#pragma unroll
    for (int c = 0; c < 16; ++c) S += ps[c] * __expf(pm[c] - gm);
    out[n] = gm + logf(S) - 0.5f * norm[n] + logc - LOGM;
}

// ---------------------------------------------------------------------------
extern "C" void kernel_launch(void* const* d_in, const int* in_sizes, int n_in,
                              void* d_out, int out_size, void* d_ws, size_t ws_size,
                              hipStream_t stream) {
    const float* samples = (const float*)d_in[0];  // 8192*784
    const float* x       = (const float*)d_in[1];  // 4096*784
    const float* stdv    = (const float*)d_in[2];  // 784
    float* out = (float*)d_out;                    // 8192

    char* ws = (char*)d_ws;
    // U fp8 (8192*896) | V fp8 (4096*896) | norm (12288 f32) | pmax | psum
    u8*    U    = (u8*)ws;                        //  7,340,032 B
    u8*    V    = (u8*)(ws + 7340032);            //  3,670,016 B
    float* norm = (float*)(ws + 11010048);        //     49,152 B
    float* pmax = (float*)(ws + 11059200);        //    524,288 B
    float* psum = (float*)(ws + 11583488);        //    524,288 B  (total ~12.1 MB)

    k_prep<<<(N_ROWS + M_ROWS) / 8, 256, 0, stream>>>(samples, x, stdv, U, norm);
    k_gemm<<<dim3(M_ROWS / 256, N_ROWS / 256), 512, 0, stream>>>(U, V, norm + N_ROWS, pmax, psum);
    k_final<<<N_ROWS / 256, 256, 0, stream>>>(pmax, psum, norm, stdv, out);
}